// Round 3
// baseline (4267.122 us; speedup 1.0000x reference)
//
#include <hip/hip_runtime.h>

constexpr int SP = 16*56*56;      // 50176 spatial per batch
constexpr int P  = 2*SP;          // 100352 positions
constexpr float EPSV = 1e-5f;

// ws layout (floats): A (canonical 64-ch feature), C (sv buffer), stats
constexpr size_t SZ_A   = (size_t)2*64*SP;   // 6422528
constexpr size_t OFF_A  = 0;
constexpr size_t OFF_C  = SZ_A;
constexpr size_t OFF_ST = OFF_C + SZ_A;      // 4096 floats of stats

// ---------------- down-projection 128->64 + bn1 stats ----------------
__global__ void __launch_bounds__(256) kern_down(
    const float* __restrict__ x, const float* __restrict__ w,
    float* __restrict__ A, float* __restrict__ st)
{
  __shared__ float xs[128*64];
  __shared__ float wt[64*129];
  __shared__ float ssum[64], ssq[64];
  const int t = threadIdx.x;
  if (t < 64) { ssum[t] = 0.f; ssq[t] = 0.f; }
  const int p0 = blockIdx.x * 64;
  const int n = p0 / SP, rem = p0 % SP;
  const float* xb = x + (size_t)n*128*SP + rem;
  for (int e = t; e < 128*64; e += 256) {
    int c = e >> 6, p = e & 63;
    xs[e] = xb[(size_t)c*SP + p];
  }
  for (int e = t; e < 64*128; e += 256) {
    int o = e >> 7, c = e & 127;
    wt[o*129 + c] = w[e];
  }
  __syncthreads();
  const int og = t & 15, pg = t >> 4;
  float acc[4][4] = {};
  for (int c = 0; c < 128; ++c) {
    float xv[4], wv[4];
    #pragma unroll
    for (int j = 0; j < 4; ++j) xv[j] = xs[c*64 + pg*4 + j];
    #pragma unroll
    for (int i = 0; i < 4; ++i) wv[i] = wt[(og*4+i)*129 + c];
    #pragma unroll
    for (int i = 0; i < 4; ++i) {
      #pragma unroll
      for (int j = 0; j < 4; ++j) acc[i][j] = fmaf(wv[i], xv[j], acc[i][j]);
    }
  }
  float* Ab = A + (size_t)n*64*SP + rem;
  #pragma unroll
  for (int i = 0; i < 4; ++i) {
    const int o = og*4 + i;
    float s1 = 0.f, s2 = 0.f;
    #pragma unroll
    for (int j = 0; j < 4; ++j) { float v = acc[i][j]; s1 += v; s2 += v*v; }
    float4 v4 = make_float4(acc[i][0], acc[i][1], acc[i][2], acc[i][3]);
    *reinterpret_cast<float4*>(Ab + (size_t)o*SP + pg*4) = v4;
    atomicAdd(&ssum[o], s1);
    atomicAdd(&ssq[o], s2);
  }
  __syncthreads();
  if (t < 64) { atomicAdd(&st[t], ssum[t]); atomicAdd(&st[64+t], ssq[t]); }
}

// ---------------- up-projection 64->128 (+relu on load) + bn2 stats ----------------
__global__ void __launch_bounds__(256) kern_up(
    const float* __restrict__ A, const float* __restrict__ w,
    float* __restrict__ U, float* __restrict__ st)
{
  __shared__ float xs[64*64];
  __shared__ float wt[128*65];
  __shared__ float ssum[128], ssq[128];
  const int t = threadIdx.x;
  if (t < 128) { ssum[t]=0.f; ssq[t]=0.f; }
  const int p0 = blockIdx.x*64;
  const int n = p0/SP, rem = p0%SP;
  const float* Ab = A + (size_t)n*64*SP + rem;
  for (int e = t; e < 64*64; e += 256) {
    int c = e >> 6, p = e & 63;
    xs[e] = fmaxf(Ab[(size_t)c*SP + p], 0.f);
  }
  for (int e = t; e < 128*64; e += 256) {
    int o = e >> 6, c = e & 63;
    wt[o*65 + c] = w[e];
  }
  __syncthreads();
  const int og = t & 31, pg = t >> 5;   // o = og*4+i (128), p = pg*8+j (64)
  float acc[4][8] = {};
  for (int c = 0; c < 64; ++c) {
    float xv[8];
    #pragma unroll
    for (int j = 0; j < 8; ++j) xv[j] = xs[c*64 + pg*8 + j];
    #pragma unroll
    for (int i = 0; i < 4; ++i) {
      float wv = wt[(og*4+i)*65 + c];
      #pragma unroll
      for (int j = 0; j < 8; ++j) acc[i][j] = fmaf(wv, xv[j], acc[i][j]);
    }
  }
  float* Ub = U + (size_t)n*128*SP + rem;
  #pragma unroll
  for (int i = 0; i < 4; ++i) {
    const int o = og*4+i;
    float s1=0.f, s2=0.f;
    #pragma unroll
    for (int j = 0; j < 8; ++j) { float v = acc[i][j]; s1 += v; s2 += v*v; }
    float4 a = make_float4(acc[i][0],acc[i][1],acc[i][2],acc[i][3]);
    float4 b = make_float4(acc[i][4],acc[i][5],acc[i][6],acc[i][7]);
    *reinterpret_cast<float4*>(Ub + (size_t)o*SP + pg*8)     = a;
    *reinterpret_cast<float4*>(Ub + (size_t)o*SP + pg*8 + 4) = b;
    atomicAdd(&ssum[o], s1); atomicAdd(&ssq[o], s2);
  }
  __syncthreads();
  if (t < 128) { atomicAdd(&st[t], ssum[t]); atomicAdd(&st[128+t], ssq[t]); }
}

// ---------------- qkv projection (gathered per direction) + bnq stats ----------------
// DIR 0: 'x'  b=(n,s,w)  attn over h   DIR 1: 'y' b=(n,s,h) over w   DIR 2: 'seq' b=(n,h,w) over s
template<int DIR, bool FIRST>
__global__ void __launch_bounds__(256) kern_qkv(
    const float* __restrict__ A, const float* __restrict__ w,
    const float* __restrict__ sc1, const float* __restrict__ sh1,
    float* __restrict__ Bq, float* __restrict__ st)
{
  constexpr int H = (DIR==2) ? 16 : 56;
  constexpr int SHJ = H/8;
  __shared__ float xs[64*H];
  __shared__ float wt[128*65];
  __shared__ float ssum[128], ssq[128];
  const int t = threadIdx.x;
  if (t < 128) { ssum[t]=0.f; ssq[t]=0.f; }
  const int b = blockIdx.x;
  size_t base; int strT;
  if (DIR == 0)      { int n=b/896,  r=b%896,  s=r/56, ww=r%56; base=(size_t)n*64*SP + s*3136 + ww;    strT=56;   }
  else if (DIR == 1) { int n=b/896,  r=b%896,  s=r/56, y=r%56;  base=(size_t)n*64*SP + s*3136 + y*56;  strT=1;    }
  else               { int n=b/3136, r=b%3136, y=r/56, ww=r%56; base=(size_t)n*64*SP + y*56 + ww;      strT=3136; }
  for (int e = t; e < 64*H; e += 256) {
    int c = e / H, j = e % H;
    float v = A[base + (size_t)c*SP + (size_t)j*strT];
    if (FIRST) v = fmaxf(fmaf(v, sc1[c], sh1[c]), 0.f);   // bn1 + relu folded into first gather
    xs[e] = v;
  }
  for (int e = t; e < 128*64; e += 256) { int o=e>>6, c=e&63; wt[o*65+c]=w[e]; }
  __syncthreads();
  const int og = t & 31, hg = t >> 5;
  float acc[4][SHJ];
  #pragma unroll
  for (int i=0;i<4;++i) {
    #pragma unroll
    for (int j=0;j<SHJ;++j) acc[i][j]=0.f;
  }
  for (int c = 0; c < 64; ++c) {
    float xv[SHJ];
    #pragma unroll
    for (int j = 0; j < SHJ; ++j) xv[j] = xs[c*H + hg*SHJ + j];
    #pragma unroll
    for (int i = 0; i < 4; ++i) {
      float wv = wt[(og*4+i)*65 + c];
      #pragma unroll
      for (int j = 0; j < SHJ; ++j) acc[i][j] = fmaf(wv, xv[j], acc[i][j]);
    }
  }
  float* ob = Bq + (size_t)b*128*H;
  #pragma unroll
  for (int i = 0; i < 4; ++i) {
    const int o = og*4+i;
    float s1=0.f, s2=0.f;
    #pragma unroll
    for (int j = 0; j < SHJ; ++j) {
      float v = acc[i][j];
      ob[o*H + hg*SHJ + j] = v;
      s1 += v; s2 += v*v;
    }
    atomicAdd(&ssum[o], s1); atomicAdd(&ssq[o], s2);
  }
  __syncthreads();
  if (t < 128) { atomicAdd(&st[t], ssum[t]); atomicAdd(&st[128+t], ssq[t]); }
}

// ---------------- scores pass 1: per-group sum/sumsq of qk ----------------
template<int H>
__global__ void __launch_bounds__(256) kern_pass1(
    const float* __restrict__ Bq, const float* __restrict__ qsc,
    const float* __restrict__ qsh, float* __restrict__ st)
{
  constexpr int PW = (H==16) ? 4 : 1;
  const int wave = threadIdx.x >> 6, lane = threadIdx.x & 63;
  const int sub = (PW==1) ? 0 : (lane >> 4);
  const int i = (PW==1) ? lane : (lane & 15);
  __shared__ float kls[4][4*H*PW];
  float* klw = kls[wave];
  const int pair0 = (blockIdx.x*4 + wave)*PW;
  for (int e = lane; e < 4*H*PW; e += 64) {
    int sp = e / (4*H), r = e % (4*H);
    int c = r / H, j = r % H;
    int pr = pair0 + sp, bb = pr >> 3, g = pr & 7;
    int o = g*16 + 4 + c;
    klw[e] = fmaf(Bq[((size_t)bb*128 + o)*H + j], qsc[o], qsh[o]);
  }
  __syncthreads();
  const int pr = pair0 + sub, bb = pr >> 3, g = pr & 7;
  const float* kp = klw + sub*4*H;
  const bool act = (i < H);
  float q[4];
  #pragma unroll
  for (int c = 0; c < 4; ++c) {
    int o = g*16 + c;
    q[c] = act ? fmaf(Bq[((size_t)bb*128 + o)*H + i], qsc[o], qsh[o]) : 0.f;
  }
  float s1 = 0.f, s2 = 0.f;
  #pragma unroll
  for (int j = 0; j < H; ++j) {
    float s = q[0]*kp[j] + q[1]*kp[H+j] + q[2]*kp[2*H+j] + q[3]*kp[3*H+j];
    s1 += s; s2 += s*s;
  }
  #pragma unroll
  for (int off = (PW==1?32:8); off >= 1; off >>= 1) {
    s1 += __shfl_xor(s1, off);
    s2 += __shfl_xor(s2, off);
  }
  if ((lane & (PW==1?63:15)) == 0) { atomicAdd(&st[g], s1); atomicAdd(&st[8+g], s2); }
}

// ---------------- scores pass 2: softmax(scale*qk) @ v, bno stats ----------------
template<int H>
__global__ void __launch_bounds__(256) kern_attn(
    const float* __restrict__ Bq, const float* __restrict__ qsc,
    const float* __restrict__ qsh, const float* __restrict__ ssc,
    float* __restrict__ C, float* __restrict__ st)
{
  constexpr int PW = (H==16) ? 4 : 1;
  const int wave = threadIdx.x >> 6, lane = threadIdx.x & 63;
  const int sub = (PW==1) ? 0 : (lane >> 4);
  const int i = (PW==1) ? lane : (lane & 15);
  __shared__ float kv[4][12*H*PW];
  float* kvw = kv[wave];
  const int pair0 = (blockIdx.x*4 + wave)*PW;
  for (int e = lane; e < 12*H*PW; e += 64) {
    int sp = e / (12*H), r = e % (12*H);
    int c = r / H, j = r % H;
    int pr = pair0 + sp, bb = pr >> 3, g = pr & 7;
    int o = g*16 + 4 + c;                 // k channels then v channels
    kvw[e] = fmaf(Bq[((size_t)bb*128 + o)*H + j], qsc[o], qsh[o]);
  }
  __syncthreads();
  const int pr = pair0 + sub, bb = pr >> 3, g = pr & 7;
  const float* kp = kvw + sub*12*H;
  const bool act = (i < H);
  float q[4];
  #pragma unroll
  for (int c = 0; c < 4; ++c) {
    int o = g*16 + c;
    q[c] = act ? fmaf(Bq[((size_t)bb*128 + o)*H + i], qsc[o], qsh[o]) : 0.f;
  }
  const float As = ssc[g];   // bns shift cancels in softmax over j
  float tv[H];
  #pragma unroll
  for (int j = 0; j < H; ++j)
    tv[j] = As * (q[0]*kp[j] + q[1]*kp[H+j] + q[2]*kp[2*H+j] + q[3]*kp[3*H+j]);
  float m = tv[0];
  #pragma unroll
  for (int j = 1; j < H; ++j) m = fmaxf(m, tv[j]);
  float den = 0.f;
  #pragma unroll
  for (int j = 0; j < H; ++j) { float e = __expf(tv[j]-m); tv[j] = e; den += e; }
  const float inv = 1.f/den;
  #pragma unroll
  for (int c = 0; c < 8; ++c) {
    float a = 0.f;
    #pragma unroll
    for (int j = 0; j < H; ++j) a = fmaf(tv[j], kp[(4+c)*H + j], a);
    a *= inv;
    float vv = act ? a : 0.f;
    if (act) C[((size_t)bb*64 + g*8 + c)*H + i] = vv;
    float s1 = vv, s2 = vv*vv;
    #pragma unroll
    for (int off = (PW==1?32:8); off >= 1; off >>= 1) {
      s1 += __shfl_xor(s1, off);
      s2 += __shfl_xor(s2, off);
    }
    if ((lane & (PW==1?63:15)) == 0) { atomicAdd(&st[g*8+c], s1); atomicAdd(&st[64+g*8+c], s2); }
  }
}

// ---------------- scatter sv back to canonical layout, bno normalize ----------------
__global__ void __launch_bounds__(256) kern_scat0(   // dir x: transpose (w,h)
    const float* __restrict__ C, const float* __restrict__ osc,
    const float* __restrict__ osh, float* __restrict__ A)
{
  __shared__ float tile[56*57];
  const int bid = blockIdx.x;
  const int c = bid & 63, s = (bid >> 6) & 15, n = bid >> 10;
  const float sc = osc[c], sh = osh[c];
  const size_t cb = ((size_t)(n*16+s)*56)*3584 + c*56;      // + w*3584 + h
  for (int e = threadIdx.x; e < 3136; e += 256) {
    int w = e/56, h = e%56;
    tile[w*57+h] = C[cb + (size_t)w*3584 + h];
  }
  __syncthreads();
  const size_t ab = ((size_t)(n*64+c)*16+s)*3136;           // + h*56 + w
  for (int e = threadIdx.x; e < 3136; e += 256) {
    int h = e/56, w = e%56;
    A[ab + e] = fmaf(tile[w*57+h], sc, sh);
  }
}

__global__ void __launch_bounds__(256) kern_scat1(   // dir y: layout-aligned copy
    const float* __restrict__ C, const float* __restrict__ osc,
    const float* __restrict__ osh, float* __restrict__ A)
{
  const int e = blockIdx.x*256 + threadIdx.x;
  if (e >= 1792*64*56) return;
  const int w = e % 56, c = (e/56) & 63, b = e / (56*64);
  const int n = b/896, r = b%896, s = r/56, y = r%56;
  A[((size_t)(n*64+c)*16+s)*3136 + y*56 + w] = fmaf(C[e], osc[c], osh[c]);
}

__global__ void __launch_bounds__(256) kern_scat2(   // dir seq: transpose (w,s)
    const float* __restrict__ C, const float* __restrict__ osc,
    const float* __restrict__ osh, float* __restrict__ A)
{
  __shared__ float tile[56*17];
  const int bid = blockIdx.x;
  const int y = bid % 56, c = (bid/56) & 63, n = bid / 3584;
  const float sc = osc[c], sh = osh[c];
  const size_t cb = ((size_t)(n*56+y)*56)*1024 + c*16;      // + w*1024 + s
  for (int e = threadIdx.x; e < 896; e += 256) {
    int w = e >> 4, s = e & 15;
    tile[w*17+s] = C[cb + (size_t)w*1024 + s];
  }
  __syncthreads();
  const size_t ab = (size_t)(n*64+c)*16*3136 + y*56;        // + s*3136 + w
  for (int e = threadIdx.x; e < 896; e += 256) {
    int s = e/56, w = e%56;
    A[ab + (size_t)s*3136 + w] = fmaf(tile[w*17+s], sc, sh);
  }
}

// ---------------- BN finalize: scale/shift from sums ----------------
__global__ void kern_fin_bn(float* __restrict__ st, const float* __restrict__ g,
                            const float* __restrict__ b, int nch, float invc)
{
  const int t = threadIdx.x;
  if (t < nch) {
    float mean = st[t]*invc;
    float var  = st[nch+t]*invc - mean*mean;
    float sc   = g[t]*rsqrtf(var + EPSV);
    st[2*nch+t] = sc;
    st[3*nch+t] = b[t] - mean*sc;
  }
}

// ---------------- final: relu(bn2(U) + identity) ----------------
__global__ void __launch_bounds__(256) kern_final(
    float* __restrict__ U, const float* __restrict__ x,
    const float* __restrict__ sc, const float* __restrict__ sh,
    float* __restrict__ out)
{
  const int idx = blockIdx.x*256 + threadIdx.x;   // one float4 each
  if (idx >= P*128/4) return;
  const int e = idx*4;
  const int o = (e / SP) & 127;
  float4 u  = *reinterpret_cast<const float4*>(U + e);
  float4 xv = *reinterpret_cast<const float4*>(x + e);
  const float s = sc[o], h = sh[o];
  float4 r;
  r.x = fmaxf(fmaf(u.x, s, h) + xv.x, 0.f);
  r.y = fmaxf(fmaf(u.y, s, h) + xv.y, 0.f);
  r.z = fmaxf(fmaf(u.z, s, h) + xv.z, 0.f);
  r.w = fmaxf(fmaf(u.w, s, h) + xv.w, 0.f);
  *reinterpret_cast<float4*>(out + e) = r;
}

extern "C" void kernel_launch(void* const* d_in, const int* in_sizes, int n_in,
                              void* d_out, int out_size, void* d_ws, size_t ws_size,
                              hipStream_t stream)
{
  const float* x    = (const float*)d_in[0];
  const float* cdw  = (const float*)d_in[1];
  const float* bn1g = (const float*)d_in[2];
  const float* bn1b = (const float*)d_in[3];
  const float* qkvw = (const float*)d_in[4];
  const float* bnqg = (const float*)d_in[5];
  const float* bnqb = (const float*)d_in[6];
  const float* bnsg = (const float*)d_in[7];
  const float* bnsb = (const float*)d_in[8];
  const float* bnog = (const float*)d_in[9];
  const float* bnob = (const float*)d_in[10];
  const float* cuw  = (const float*)d_in[11];
  const float* bn2g = (const float*)d_in[12];
  const float* bn2b = (const float*)d_in[13];
  float* out = (float*)d_out;
  float* ws  = (float*)d_ws;

  float* A   = ws + OFF_A;
  float* C   = ws + OFF_C;
  float* st  = ws + OFF_ST;
  float* Bq  = out;          // 12,845,056 floats: qkv buffer / up-proj buffer / final output

  hipMemsetAsync(st, 0, 4096*sizeof(float), stream);

  const float invP = 1.f/100352.f;

  // stage A: down-proj + bn1
  kern_down<<<P/64, 256, 0, stream>>>(x, cdw, A, st);
  kern_fin_bn<<<1, 128, 0, stream>>>(st, bn1g, bn1b, 64, invP);

  // direction 0: 'x'
  {
    float* stq = st + 256; float* sts = stq + 512; float* sto = stq + 544;
    kern_qkv<0,true><<<1792, 256, 0, stream>>>(A, qkvw, st+128, st+192, Bq, stq);
    kern_fin_bn<<<1, 128, 0, stream>>>(stq, bnqg, bnqb, 128, invP);
    kern_pass1<56><<<3584, 256, 0, stream>>>(Bq, stq+256, stq+384, sts);
    kern_fin_bn<<<1, 128, 0, stream>>>(sts, bnsg, bnsb, 8, 1.f/5619712.f);
    kern_attn<56><<<3584, 256, 0, stream>>>(Bq, stq+256, stq+384, sts+16, C, sto);
    kern_fin_bn<<<1, 128, 0, stream>>>(sto, bnog, bnob, 64, invP);
    kern_scat0<<<2048, 256, 0, stream>>>(C, sto+128, sto+192, A);
  }
  // direction 1: 'y'
  {
    float* stq = st + 256 + 1024; float* sts = stq + 512; float* sto = stq + 544;
    kern_qkv<1,false><<<1792, 256, 0, stream>>>(A, qkvw+8192, st, st, Bq, stq);
    kern_fin_bn<<<1, 128, 0, stream>>>(stq, bnqg+128, bnqb+128, 128, invP);
    kern_pass1<56><<<3584, 256, 0, stream>>>(Bq, stq+256, stq+384, sts);
    kern_fin_bn<<<1, 128, 0, stream>>>(sts, bnsg+8, bnsb+8, 8, 1.f/5619712.f);
    kern_attn<56><<<3584, 256, 0, stream>>>(Bq, stq+256, stq+384, sts+16, C, sto);
    kern_fin_bn<<<1, 128, 0, stream>>>(sto, bnog+64, bnob+64, 64, invP);
    kern_scat1<<<25088, 256, 0, stream>>>(C, sto+128, sto+192, A);
  }
  // direction 2: 'seq'
  {
    float* stq = st + 256 + 2048; float* sts = stq + 512; float* sto = stq + 544;
    kern_qkv<2,false><<<6272, 256, 0, stream>>>(A, qkvw+16384, st, st, Bq, stq);
    kern_fin_bn<<<1, 128, 0, stream>>>(stq, bnqg+256, bnqb+256, 128, invP);
    kern_pass1<16><<<3136, 256, 0, stream>>>(Bq, stq+256, stq+384, sts);
    kern_fin_bn<<<1, 128, 0, stream>>>(sts, bnsg+16, bnsb+16, 8, 1.f/1605632.f);
    kern_attn<16><<<3136, 256, 0, stream>>>(Bq, stq+256, stq+384, sts+16, C, sto);
    kern_fin_bn<<<1, 128, 0, stream>>>(sto, bnog+128, bnob+128, 64, invP);
    kern_scat2<<<7168, 256, 0, stream>>>(C, sto+128, sto+192, A);
  }

  // stage B: relu -> up-proj + bn2 -> residual + relu
  float* st2 = st + 3328;
  kern_up<<<P/64, 256, 0, stream>>>(A, cuw, Bq, st2);
  kern_fin_bn<<<1, 128, 0, stream>>>(st2, bn2g, bn2b, 128, invP);
  kern_final<<<P*128/4/256, 256, 0, stream>>>(Bq, x, st2+256, st2+384, out);
}